// Round 5
// baseline (373.962 us; speedup 1.0000x reference)
//
#include <hip/hip_runtime.h>
#include <hip/hip_bf16.h>

// Sizes fixed by the problem
#define TT 240

typedef __attribute__((ext_vector_type(8))) short bf16x8;
typedef __attribute__((ext_vector_type(4))) float f32x4;

static __device__ __forceinline__ short f2bf(float f) {
    union { float f; unsigned int u; } c; c.f = f;
    return (short)((c.u + 0x8000u) >> 16);     // round-to-nearest (ties up); inputs finite
}
static __device__ __forceinline__ unsigned int cvtpk(float lo, float hi) {
    unsigned int r;
    asm("v_cvt_pk_bf16_f32 %0, %1, %2" : "=v"(r) : "v"(lo), "v"(hi));
    return r;
}
static __device__ __forceinline__ float fexp2(float x) { return __builtin_amdgcn_exp2f(x); }
static __device__ __forceinline__ float frcp(float x)  { return __builtin_amdgcn_rcpf(x); }
#define LOG2E 1.4426950408889634f
static __device__ __forceinline__ float sigm(float x)  { return frcp(1.f + fexp2(-LOG2E * x)); }
static __device__ __forceinline__ float tanh_(float x) { return 2.f * frcp(1.f + fexp2(-2.f * LOG2E * x)) - 1.f; }

// ---------------------------------------------------------------------------
// Weight repack (bf16):
//  woutB: [48][21600]  rows 40..47 zero   (vectorized: 16B in / 16B out)
//  wencP: [288][192]   rows = gate*96+h (gates i,g,o; f dropped), zero-padded
//  wdecP: [288][96]
// ---------------------------------------------------------------------------
__global__ __launch_bounds__(256) void k_prep(
    const float* __restrict__ outW, const float* __restrict__ encW,
    const float* __restrict__ decW,
    short* __restrict__ woutB, short* __restrict__ wencP, short* __restrict__ wdecP)
{
    int idx = blockIdx.x * 256 + threadIdx.x;
    if (idx < 129600) {                       // 48*21600/8 granules of 8 shorts
        int row = idx / 2700, v = idx - row * 2700;
        uint4 w = {0u, 0u, 0u, 0u};
        if (row < 40) {
            const float* s = outW + row * 21600 + v * 8;
            f32x4 a = *(const f32x4*)(s);
            f32x4 b = *(const f32x4*)(s + 4);
            w.x = cvtpk(a[0], a[1]); w.y = cvtpk(a[2], a[3]);
            w.z = cvtpk(b[0], b[1]); w.w = cvtpk(b[2], b[3]);
        }
        *(uint4*)(woutB + row * 21600 + v * 8) = w;
        return;
    }
    idx -= 129600;
    if (idx < 288 * 192) {
        int row = idx / 192, k = idx - row * 192;
        int gi = row / 96, h = row - gi * 96;
        float v = 0.f;
        if (h < 90 && k < 180) {
            int srow = (gi == 0 ? 0 : (gi == 1 ? 180 : 270)) + h;
            v = encW[srow * 180 + k];
        }
        wencP[idx] = f2bf(v);
        return;
    }
    idx -= 288 * 192;
    if (idx < 288 * 96) {
        int row = idx / 96, k = idx - row * 96;
        int gi = row / 96, h = row - gi * 96;
        float v = 0.f;
        if (h < 90 && k < 90) {
            int srow = (gi == 0 ? 0 : (gi == 1 ? 180 : 270)) + h;
            v = decW[srow * 90 + k];
        }
        wdecP[idx] = f2bf(v);
    }
}

// ---------------------------------------------------------------------------
// Stage one 60x180 x-tile (fused transpose fp32->bf16) into an LDS buffer.
// task (fb, v): 4 coalesced f32x4 loads, cvt_pk, 2x uint2 LDS writes.
// ---------------------------------------------------------------------------
static __device__ __forceinline__ void stage_tile(
    const float* __restrict__ xq, short (*__restrict__ Xn)[200],
    int fb1, int v1, int has2, int fb2, int v2)
{
    const float* p1 = xq + (fb1 * 4) * 240 + v1 * 4;
    f32x4 A0 = *(const f32x4*)(p1);
    f32x4 A1 = *(const f32x4*)(p1 + 240);
    f32x4 A2 = *(const f32x4*)(p1 + 480);
    f32x4 A3 = *(const f32x4*)(p1 + 720);
    f32x4 B0, B1, B2, B3;
    if (has2) {
        const float* p2 = xq + (fb2 * 4) * 240 + v2 * 4;
        B0 = *(const f32x4*)(p2);
        B1 = *(const f32x4*)(p2 + 240);
        B2 = *(const f32x4*)(p2 + 480);
        B3 = *(const f32x4*)(p2 + 720);
    }
    #pragma unroll
    for (int i = 0; i < 4; ++i) {
        uint2 w;
        w.x = cvtpk(A0[i], A1[i]);
        w.y = cvtpk(A2[i], A3[i]);
        *(uint2*)(&Xn[v1 * 4 + i][fb1 * 4]) = w;
    }
    if (has2) {
        #pragma unroll
        for (int i = 0; i < 4; ++i) {
            uint2 w;
            w.x = cvtpk(B0[i], B1[i]);
            w.y = cvtpk(B2[i], B3[i]);
            *(uint2*)(&Xn[v2 * 4 + i][fb2 * 4]) = w;
        }
    }
}

// ---------------------------------------------------------------------------
// Fused encoder+decoder, 4 q-tiles per block, ping-pong pipelined.
// Block = batch b; tiles q=0..3 cover rows t = q*60..q*60+59.
// 6 waves; wave wv owns h-tile [wv*16, wv*16+16), W frags in registers.
// Per tile: [A] x ready -> enc MFMA -> [B] h1 scatter into same buffer
// (cols 0..95) + stage next tile into other buffer -> [C] dec MFMA ->
// h2 stored straight from registers (rows<60, h<90).
// ---------------------------------------------------------------------------
__global__ __launch_bounds__(384, 3) void k_ed(
    const float* __restrict__ x,
    const short* __restrict__ wencP, const short* __restrict__ wdecP,
    const float* __restrict__ eb_ih, const float* __restrict__ eb_hh,
    const float* __restrict__ db_ih, const float* __restrict__ db_hh,
    short* __restrict__ h2)
{
    __shared__ short X[2][64][200];          // 51.2 KB, ping-pong
    const int tid  = threadIdx.x;
    const int lane = tid & 63;
    const int wv   = tid >> 6;
    const int b    = blockIdx.x;
    const int r15  = lane & 15;
    const int k8   = lane >> 4;
    const int rbase = k8 * 4;

    // Encoder W fragments: 3 gates x 6 k-steps (persistent)
    bf16x8 wfE[3][6];
    #pragma unroll
    for (int g = 0; g < 3; ++g) {
        const short* wp = wencP + (g * 96 + wv * 16 + r15) * 192 + k8 * 8;
        #pragma unroll
        for (int kk = 0; kk < 6; ++kk) wfE[g][kk] = *(const bf16x8*)(wp + kk * 32);
    }
    // Decoder W fragments (loop-invariant; LICM keeps them resident)
    bf16x8 wfD[3][3];
    #pragma unroll
    for (int g = 0; g < 3; ++g) {
        const short* wp = wdecP + (g * 96 + wv * 16 + r15) * 96 + k8 * 8;
        #pragma unroll
        for (int kk = 0; kk < 3; ++kk) wfD[g][kk] = *(const bf16x8*)(wp + kk * 32);
    }

    const int h  = wv * 16 + r15;
    const int hc = (h < 90) ? h : 89;
    const float bIe = eb_ih[hc] + eb_hh[hc];
    const float bGe = eb_ih[180 + hc] + eb_hh[180 + hc];
    const float bOe = eb_ih[270 + hc] + eb_hh[270 + hc];
    const float bId = db_ih[hc] + db_hh[hc];
    const float bGd = db_ih[180 + hc] + db_hh[180 + hc];
    const float bOd = db_ih[270 + hc] + db_hh[270 + hc];

    // Zero pads for BOTH buffers: rows 60..63 (all cols), cols 180..199 (rows 0..59)
    for (int i = tid; i < 2000; i += 384) {
        int bi = (i >= 1000);
        int j  = i - bi * 1000;
        if (j < 400) {
            int r = j / 100, c = j - r * 100;
            *(unsigned int*)(&X[bi][60 + r][c * 2]) = 0u;
        } else {
            int jj = j - 400;
            int r = jj / 10, c = jj - r * 10;
            *(unsigned int*)(&X[bi][r][180 + c * 2]) = 0u;
        }
    }

    // Per-lane staging task decode (675 tasks over 384 threads)
    const int fb1 = tid / 15, v1 = tid - fb1 * 15;
    const int has2 = (tid < 291);
    const int t2 = tid + 384;
    const int fb2 = t2 / 15, v2 = t2 - fb2 * 15;
    const float* xb = x + (size_t)b * 43200;
    short* h2g = h2 + (size_t)b * 21600;

    // Prologue: stage tile 0
    stage_tile(xb, X[0], fb1, v1, has2, fb2, v2);

    int p = 0;
    #pragma unroll 1
    for (int q = 0; q < 4; ++q) {
        __syncthreads();                                   // [A] X[p] ready
        short (*Xc)[200] = X[p];

        // ---- Encoder -> h1 in registers ----
        short h1v[16];
        #pragma unroll
        for (int rs = 0; rs < 4; ++rs) {
            f32x4 aI = {0.f,0.f,0.f,0.f}, aG = {0.f,0.f,0.f,0.f}, aO = {0.f,0.f,0.f,0.f};
            #pragma unroll
            for (int kk = 0; kk < 6; ++kk) {
                bf16x8 a = *(const bf16x8*)(&Xc[rs * 16 + r15][kk * 32 + k8 * 8]);
                aI = __builtin_amdgcn_mfma_f32_16x16x32_bf16(a, wfE[0][kk], aI, 0, 0, 0);
                aG = __builtin_amdgcn_mfma_f32_16x16x32_bf16(a, wfE[1][kk], aG, 0, 0, 0);
                aO = __builtin_amdgcn_mfma_f32_16x16x32_bf16(a, wfE[2][kk], aO, 0, 0, 0);
            }
            #pragma unroll
            for (int rg = 0; rg < 4; ++rg) {
                float c  = sigm(aI[rg] + bIe) * tanh_(aG[rg] + bGe);
                float hv = sigm(aO[rg] + bOe) * tanh_(c);
                h1v[rs * 4 + rg] = f2bf(sigm(hv));         // extra sigmoid on enc out
            }
        }
        __syncthreads();                                   // [B] enc reads done

        // h1 scatter into Xc cols 0..95 (x data dead)
        #pragma unroll
        for (int j = 0; j < 16; ++j)
            Xc[(j >> 2) * 16 + rbase + (j & 3)][h] = h1v[j];

        // stage next tile into the other buffer (safe after [A])
        if (q < 3)
            stage_tile(xb + (q + 1) * 60, X[p ^ 1], fb1, v1, has2, fb2, v2);

        __syncthreads();                                   // [C] h1 ready

        // ---- Decoder -> h2 stored direct from registers ----
        #pragma unroll
        for (int rs = 0; rs < 4; ++rs) {
            f32x4 aI = {0.f,0.f,0.f,0.f}, aG = {0.f,0.f,0.f,0.f}, aO = {0.f,0.f,0.f,0.f};
            #pragma unroll
            for (int kk = 0; kk < 3; ++kk) {
                bf16x8 a = *(const bf16x8*)(&Xc[rs * 16 + r15][kk * 32 + k8 * 8]);
                aI = __builtin_amdgcn_mfma_f32_16x16x32_bf16(a, wfD[0][kk], aI, 0, 0, 0);
                aG = __builtin_amdgcn_mfma_f32_16x16x32_bf16(a, wfD[1][kk], aG, 0, 0, 0);
                aO = __builtin_amdgcn_mfma_f32_16x16x32_bf16(a, wfD[2][kk], aO, 0, 0, 0);
            }
            if (h < 90) {
                #pragma unroll
                for (int rg = 0; rg < 4; ++rg) {
                    int row = rs * 16 + rbase + rg;
                    float c  = sigm(aI[rg] + bId) * tanh_(aG[rg] + bGd);
                    float o2 = sigm(aO[rg] + bOd) * tanh_(c);
                    if (row < 60) h2g[q * 5400 + row * 90 + h] = f2bf(o2);
                }
            }
        }
        p ^= 1;
    }
}

// ---------------------------------------------------------------------------
// Output head GEMM: logits[b][n] = sum_k h2[b][k] * woutB[n][k]
// M=B, N=48 (40 valid), K=21600 = 45 chunks x 480. Block = 256 thr (4 waves),
// 64-row M-tile, B-chunk staged in LDS (48x480, stride 488 -> 2-way-free).
// A fragments stream from global (k-contiguous dwordx4), fully unrolled.
// ---------------------------------------------------------------------------
#define KSPLIT 45
#define KST    15      // K-steps (x32) per chunk: 45*15*32 = 21600
__global__ __launch_bounds__(256) void k_out(
    const short* __restrict__ h2, const short* __restrict__ woutB,
    float* __restrict__ part, int B)
{
    __shared__ short Bs[48][488];
    const int MT  = B >> 6;              // 64-row tiles
    const int bid = blockIdx.x;
    const int kc  = bid / MT;
    const int mt  = bid - kc * MT;
    const int tid = threadIdx.x;

    {   // stage B chunk: 48 rows x 480 shorts = 2880 uint4 granules
        const int k0 = kc * 480;
        #pragma unroll
        for (int j = 0; j < 12; ++j) {
            int g = tid + 256 * j;
            if (g < 2880) {
                int r = g / 60, c = g - r * 60;
                *(uint4*)(&Bs[r][c * 8]) =
                    *(const uint4*)(woutB + (size_t)r * 21600 + k0 + c * 8);
            }
        }
    }
    __syncthreads();

    const int w = tid >> 6, lane = tid & 63;
    const int r15 = lane & 15, k8 = lane >> 4;
    const int row = mt * 64 + w * 16 + r15;
    const short* aB = h2 + (size_t)row * 21600 + kc * 480 + k8 * 8;

    f32x4 a0 = {0.f,0.f,0.f,0.f}, a1 = {0.f,0.f,0.f,0.f}, a2 = {0.f,0.f,0.f,0.f};
    #pragma unroll
    for (int ks = 0; ks < KST; ++ks) {
        bf16x8 a  = *(const bf16x8*)(aB + ks * 32);
        bf16x8 q0 = *(const bf16x8*)(&Bs[r15][ks * 32 + k8 * 8]);
        bf16x8 q1 = *(const bf16x8*)(&Bs[16 + r15][ks * 32 + k8 * 8]);
        bf16x8 q2 = *(const bf16x8*)(&Bs[32 + r15][ks * 32 + k8 * 8]);
        a0 = __builtin_amdgcn_mfma_f32_16x16x32_bf16(a, q0, a0, 0, 0, 0);
        a1 = __builtin_amdgcn_mfma_f32_16x16x32_bf16(a, q1, a1, 0, 0, 0);
        a2 = __builtin_amdgcn_mfma_f32_16x16x32_bf16(a, q2, a2, 0, 0, 0);
    }
    float* pb = part + ((size_t)kc * B + mt * 64 + w * 16) * 48;
    #pragma unroll
    for (int rg = 0; rg < 4; ++rg) {
        int r = k8 * 4 + rg;
        pb[r * 48 +      r15] = a0[rg];
        pb[r * 48 + 16 + r15] = a1[rg];
        pb[r * 48 + 32 + r15] = a2[rg];
    }
}

// ---------------------------------------------------------------------------
// Reduce partials (coalesced float4, 192 parallel lanes) + bias + softmax.
// ---------------------------------------------------------------------------
__global__ __launch_bounds__(256) void k_soft(
    const float* __restrict__ part, const float* __restrict__ outb,
    float* __restrict__ out, int B)
{
    const int b = blockIdx.x, tid = threadIdx.x;
    __shared__ f32x4 red[16][12];
    __shared__ float vals[48];
    if (tid < 192) {
        int j = tid / 12, g = tid - j * 12;
        f32x4 s = {0.f, 0.f, 0.f, 0.f};
        for (int kc = j; kc < KSPLIT; kc += 16)
            s += *(const f32x4*)(part + ((size_t)kc * B + b) * 48 + g * 4);
        red[j][g] = s;
    }
    __syncthreads();
    if (tid < 12) {
        f32x4 s = red[0][tid];
        #pragma unroll
        for (int j = 1; j < 16; ++j) s += red[j][tid];
        #pragma unroll
        for (int e = 0; e < 4; ++e) {
            int o = tid * 4 + e;
            vals[o] = s[e] + ((o < 40) ? outb[o] : 0.f);
        }
    }
    __syncthreads();
    if (tid < 4) {
        float mx = -1e30f;
        #pragma unroll
        for (int j = 0; j < 10; ++j) mx = fmaxf(mx, vals[tid * 10 + j]);
        float e[10], s = 0.f;
        #pragma unroll
        for (int j = 0; j < 10; ++j) { e[j] = fexp2(LOG2E * (vals[tid * 10 + j] - mx)); s += e[j]; }
        float inv = frcp(s);
        #pragma unroll
        for (int j = 0; j < 10; ++j) out[b * 40 + tid * 10 + j] = e[j] * inv;
    }
}

// ---------------------------------------------------------------------------
extern "C" void kernel_launch(void* const* d_in, const int* in_sizes, int n_in,
                              void* d_out, int out_size, void* d_ws, size_t ws_size,
                              hipStream_t stream)
{
    const float* x     = (const float*)d_in[0];
    const float* encW  = (const float*)d_in[1];
    const float* eb_ih = (const float*)d_in[2];
    const float* eb_hh = (const float*)d_in[3];
    const float* decW  = (const float*)d_in[4];
    const float* db_ih = (const float*)d_in[5];
    const float* db_hh = (const float*)d_in[6];
    const float* outW  = (const float*)d_in[7];
    const float* outb  = (const float*)d_in[8];
    float* out = (float*)d_out;

    const int B = in_sizes[0] / (3 * 60 * TT);

    char* ws = (char*)d_ws;
    short* woutB = (short*)ws;                       // 48*21600*2 = 2,073,600 B
    short* wencP = (short*)(ws + 2073600);           // 288*192*2  =   110,592 B
    short* wdecP = (short*)(ws + 2184192);           // 288*96*2   =    55,296 B
    short* h2    = (short*)(ws + 2239488);           // B*21600*2  = B*43,200 B
    float* part  = (float*)(ws + 2239488 + (size_t)B * 43200);  // 45*B*48*4 B

    k_prep<<<dim3(831), dim3(256), 0, stream>>>(outW, encW, decW, woutB, wencP, wdecP);
    k_ed<<<dim3(B), dim3(384), 0, stream>>>(x, wencP, wdecP, eb_ih, eb_hh,
                                            db_ih, db_hh, h2);
    k_out<<<dim3(KSPLIT * (B >> 6)), dim3(256), 0, stream>>>(h2, woutB, part, B);
    k_soft<<<dim3(B), dim3(256), 0, stream>>>(part, outb, out, B);
}

// Round 6
// 369.821 us; speedup vs baseline: 1.0112x; 1.0112x over previous
//
#include <hip/hip_runtime.h>
#include <hip/hip_bf16.h>

// Sizes fixed by the problem
#define TT 240

typedef __attribute__((ext_vector_type(8))) short bf16x8;
typedef __attribute__((ext_vector_type(4))) float f32x4;

static __device__ __forceinline__ short f2bf(float f) {
    union { float f; unsigned int u; } c; c.f = f;
    return (short)((c.u + 0x8000u) >> 16);     // round-to-nearest (ties up); inputs finite
}
static __device__ __forceinline__ unsigned int cvtpk(float lo, float hi) {
    unsigned int r;
    asm("v_cvt_pk_bf16_f32 %0, %1, %2" : "=v"(r) : "v"(lo), "v"(hi));
    return r;
}
static __device__ __forceinline__ float fexp2(float x) { return __builtin_amdgcn_exp2f(x); }
static __device__ __forceinline__ float frcp(float x)  { return __builtin_amdgcn_rcpf(x); }
#define LOG2E 1.4426950408889634f
static __device__ __forceinline__ float sigm(float x)  { return frcp(1.f + fexp2(-LOG2E * x)); }
static __device__ __forceinline__ float tanh_(float x) { return 2.f * frcp(1.f + fexp2(-2.f * LOG2E * x)) - 1.f; }

// ---------------------------------------------------------------------------
// Weight repack (bf16):
//  woutB: [48][21600]  rows 40..47 zero   (vectorized: 16B in / 16B out)
//  wencP: [288][192]   rows = gate*96+h (gates i,g,o; f dropped), zero-padded
//  wdecP: [288][96]
// ---------------------------------------------------------------------------
__global__ __launch_bounds__(256) void k_prep(
    const float* __restrict__ outW, const float* __restrict__ encW,
    const float* __restrict__ decW,
    short* __restrict__ woutB, short* __restrict__ wencP, short* __restrict__ wdecP)
{
    int idx = blockIdx.x * 256 + threadIdx.x;
    if (idx < 129600) {                       // 48*21600/8 granules of 8 shorts
        int row = idx / 2700, v = idx - row * 2700;
        uint4 w = {0u, 0u, 0u, 0u};
        if (row < 40) {
            const float* s = outW + row * 21600 + v * 8;
            f32x4 a = *(const f32x4*)(s);
            f32x4 b = *(const f32x4*)(s + 4);
            w.x = cvtpk(a[0], a[1]); w.y = cvtpk(a[2], a[3]);
            w.z = cvtpk(b[0], b[1]); w.w = cvtpk(b[2], b[3]);
        }
        *(uint4*)(woutB + row * 21600 + v * 8) = w;
        return;
    }
    idx -= 129600;
    if (idx < 288 * 192) {
        int row = idx / 192, k = idx - row * 192;
        int gi = row / 96, h = row - gi * 96;
        float v = 0.f;
        if (h < 90 && k < 180) {
            int srow = (gi == 0 ? 0 : (gi == 1 ? 180 : 270)) + h;
            v = encW[srow * 180 + k];
        }
        wencP[idx] = f2bf(v);
        return;
    }
    idx -= 288 * 192;
    if (idx < 288 * 96) {
        int row = idx / 96, k = idx - row * 96;
        int gi = row / 96, h = row - gi * 96;
        float v = 0.f;
        if (h < 90 && k < 90) {
            int srow = (gi == 0 ? 0 : (gi == 1 ? 180 : 270)) + h;
            v = decW[srow * 90 + k];
        }
        wdecP[idx] = f2bf(v);
    }
}

// ---------------------------------------------------------------------------
// Fused encoder+decoder. Block = (b, q): rows t = q*60..q*60+59 of batch b.
// Single 25.6 KB LDS buffer; register diet via GATE-MAJOR MFMA loops (only
// one gate's W fragments live at a time) + __launch_bounds__(384,3) to get
// 3 waves/SIMD (12 waves/CU). 6 waves; wave wv owns h-tile [wv*16,wv*16+16).
// Flow: stage x -> [1] -> enc (gate-major) -> [2] -> h1 scatter -> [3] ->
// dec (gate-major) -> h2 stored direct from registers.
// ---------------------------------------------------------------------------
__global__ __launch_bounds__(384, 3) void k_ed(
    const float* __restrict__ x,
    const short* __restrict__ wencP, const short* __restrict__ wdecP,
    const float* __restrict__ eb_ih, const float* __restrict__ eb_hh,
    const float* __restrict__ db_ih, const float* __restrict__ db_hh,
    short* __restrict__ h2)
{
    __shared__ short Xc[64][200];   // x tile (cols 0..191); then h1 (cols 0..95)
    const int tid  = threadIdx.x;
    const int lane = tid & 63;
    const int wv   = tid >> 6;
    const int b    = blockIdx.x >> 2;
    const int q    = blockIdx.x & 3;
    const int r15  = lane & 15;
    const int k8   = lane >> 4;
    const int rbase = k8 * 4;

    const int h  = wv * 16 + r15;
    const int hc = (h < 90) ? h : 89;
    const float bIe = eb_ih[hc] + eb_hh[hc];
    const float bGe = eb_ih[180 + hc] + eb_hh[180 + hc];
    const float bOe = eb_ih[270 + hc] + eb_hh[270 + hc];
    const float bId = db_ih[hc] + db_hh[hc];
    const float bGd = db_ih[180 + hc] + db_hh[180 + hc];
    const float bOd = db_ih[270 + hc] + db_hh[270 + hc];

    // Zero pads: rows 60..63 (cols 0..199) = 400 uints; cols 180..199 of
    // rows 0..59 = 600 uints.
    for (int i = tid; i < 1000; i += 384) {
        if (i < 400) {
            int r = i / 100, c = i - r * 100;
            *(unsigned int*)(&Xc[60 + r][c * 2]) = 0u;
        } else {
            int j = i - 400, r = j / 10, c = j - r * 10;
            *(unsigned int*)(&Xc[r][180 + c * 2]) = 0u;
        }
    }

    // Stage x tile: 675 tasks; task (fb,v): 4 coalesced f32x4 loads of
    // x[b][fb*4..+3][t0+v*4..+3], cvt_pk transpose, 2 uint2 LDS writes each.
    {
        const float* xq = x + (size_t)b * 43200 + q * 60;
        const int fb1 = tid / 15, v1 = tid - fb1 * 15;
        {
            const float* p = xq + (fb1 * 4) * 240 + v1 * 4;
            f32x4 A0 = *(const f32x4*)(p);
            f32x4 A1 = *(const f32x4*)(p + 240);
            f32x4 A2 = *(const f32x4*)(p + 480);
            f32x4 A3 = *(const f32x4*)(p + 720);
            #pragma unroll
            for (int i = 0; i < 4; ++i) {
                uint2 w;
                w.x = cvtpk(A0[i], A1[i]);
                w.y = cvtpk(A2[i], A3[i]);
                *(uint2*)(&Xc[v1 * 4 + i][fb1 * 4]) = w;
            }
        }
        if (tid < 291) {
            int t2 = tid + 384;
            int fb2 = t2 / 15, v2 = t2 - fb2 * 15;
            const float* p = xq + (fb2 * 4) * 240 + v2 * 4;
            f32x4 A0 = *(const f32x4*)(p);
            f32x4 A1 = *(const f32x4*)(p + 240);
            f32x4 A2 = *(const f32x4*)(p + 480);
            f32x4 A3 = *(const f32x4*)(p + 720);
            #pragma unroll
            for (int i = 0; i < 4; ++i) {
                uint2 w;
                w.x = cvtpk(A0[i], A1[i]);
                w.y = cvtpk(A2[i], A3[i]);
                *(uint2*)(&Xc[v2 * 4 + i][fb2 * 4]) = w;
            }
        }
    }
    __syncthreads();                                   // [1] x ready

    // ---- Encoder, gate-major: acc for all 3 gates, one gate's W live ----
    f32x4 accE[3][4];
    #pragma unroll
    for (int g = 0; g < 3; ++g) {
        bf16x8 wf[6];
        const short* wp = wencP + (g * 96 + wv * 16 + r15) * 192 + k8 * 8;
        #pragma unroll
        for (int kk = 0; kk < 6; ++kk) wf[kk] = *(const bf16x8*)(wp + kk * 32);
        #pragma unroll
        for (int rs = 0; rs < 4; ++rs) {
            f32x4 a4 = {0.f, 0.f, 0.f, 0.f};
            #pragma unroll
            for (int kk = 0; kk < 6; ++kk) {
                bf16x8 a = *(const bf16x8*)(&Xc[rs * 16 + r15][kk * 32 + k8 * 8]);
                a4 = __builtin_amdgcn_mfma_f32_16x16x32_bf16(a, wf[kk], a4, 0, 0, 0);
            }
            accE[g][rs] = a4;
        }
    }
    // Activations -> h1 bf16 in registers
    unsigned short h1v[16];
    #pragma unroll
    for (int rs = 0; rs < 4; ++rs) {
        #pragma unroll
        for (int rg = 0; rg < 4; ++rg) {
            float c  = sigm(accE[0][rs][rg] + bIe) * tanh_(accE[1][rs][rg] + bGe);
            float hv = sigm(accE[2][rs][rg] + bOe) * tanh_(c);
            h1v[rs * 4 + rg] = (unsigned short)f2bf(sigm(hv));  // extra sigmoid
        }
    }
    __syncthreads();                                   // [2] enc reads of Xc done

    // h1 scatter into Xc cols 0..95 (x data dead)
    #pragma unroll
    for (int j = 0; j < 16; ++j)
        Xc[(j >> 2) * 16 + rbase + (j & 3)][h] = (short)h1v[j];
    __syncthreads();                                   // [3] h1 ready

    // ---- Decoder, gate-major; h2 stored direct from registers ----
    f32x4 accD[3][4];
    #pragma unroll
    for (int g = 0; g < 3; ++g) {
        bf16x8 wf[3];
        const short* wp = wdecP + (g * 96 + wv * 16 + r15) * 96 + k8 * 8;
        #pragma unroll
        for (int kk = 0; kk < 3; ++kk) wf[kk] = *(const bf16x8*)(wp + kk * 32);
        #pragma unroll
        for (int rs = 0; rs < 4; ++rs) {
            f32x4 a4 = {0.f, 0.f, 0.f, 0.f};
            #pragma unroll
            for (int kk = 0; kk < 3; ++kk) {
                bf16x8 a = *(const bf16x8*)(&Xc[rs * 16 + r15][kk * 32 + k8 * 8]);
                a4 = __builtin_amdgcn_mfma_f32_16x16x32_bf16(a, wf[kk], a4, 0, 0, 0);
            }
            accD[g][rs] = a4;
        }
    }
    if (h < 90) {
        short* h2g = h2 + (size_t)b * 21600 + q * 5400;
        #pragma unroll
        for (int rs = 0; rs < 4; ++rs) {
            #pragma unroll
            for (int rg = 0; rg < 4; ++rg) {
                int row = rs * 16 + rbase + rg;
                float c  = sigm(accD[0][rs][rg] + bId) * tanh_(accD[1][rs][rg] + bGd);
                float o2 = sigm(accD[2][rs][rg] + bOd) * tanh_(c);
                if (row < 60) h2g[row * 90 + h] = f2bf(o2);
            }
        }
    }
}

// ---------------------------------------------------------------------------
// Output head GEMM: logits[b][n] = sum_k h2[b][k] * woutB[n][k]
// M=B, N=48 (40 valid), K=21600 = 45 chunks x 480. Block = 256 thr (4 waves),
// 64-row M-tile, B-chunk staged in LDS (48x480, stride 488 -> 2-way-free).
// A fragments stream from global (k-contiguous dwordx4), fully unrolled.
// ---------------------------------------------------------------------------
#define KSPLIT 45
#define KST    15      // K-steps (x32) per chunk: 45*15*32 = 21600
__global__ __launch_bounds__(256) void k_out(
    const short* __restrict__ h2, const short* __restrict__ woutB,
    float* __restrict__ part, int B)
{
    __shared__ short Bs[48][488];
    const int MT  = B >> 6;              // 64-row tiles
    const int bid = blockIdx.x;
    const int kc  = bid / MT;
    const int mt  = bid - kc * MT;
    const int tid = threadIdx.x;

    {   // stage B chunk: 48 rows x 480 shorts = 2880 uint4 granules
        const int k0 = kc * 480;
        #pragma unroll
        for (int j = 0; j < 12; ++j) {
            int g = tid + 256 * j;
            if (g < 2880) {
                int r = g / 60, c = g - r * 60;
                *(uint4*)(&Bs[r][c * 8]) =
                    *(const uint4*)(woutB + (size_t)r * 21600 + k0 + c * 8);
            }
        }
    }
    __syncthreads();

    const int w = tid >> 6, lane = tid & 63;
    const int r15 = lane & 15, k8 = lane >> 4;
    const int row = mt * 64 + w * 16 + r15;
    const short* aB = h2 + (size_t)row * 21600 + kc * 480 + k8 * 8;

    f32x4 a0 = {0.f,0.f,0.f,0.f}, a1 = {0.f,0.f,0.f,0.f}, a2 = {0.f,0.f,0.f,0.f};
    #pragma unroll
    for (int ks = 0; ks < KST; ++ks) {
        bf16x8 a  = *(const bf16x8*)(aB + ks * 32);
        bf16x8 q0 = *(const bf16x8*)(&Bs[r15][ks * 32 + k8 * 8]);
        bf16x8 q1 = *(const bf16x8*)(&Bs[16 + r15][ks * 32 + k8 * 8]);
        bf16x8 q2 = *(const bf16x8*)(&Bs[32 + r15][ks * 32 + k8 * 8]);
        a0 = __builtin_amdgcn_mfma_f32_16x16x32_bf16(a, q0, a0, 0, 0, 0);
        a1 = __builtin_amdgcn_mfma_f32_16x16x32_bf16(a, q1, a1, 0, 0, 0);
        a2 = __builtin_amdgcn_mfma_f32_16x16x32_bf16(a, q2, a2, 0, 0, 0);
    }
    float* pb = part + ((size_t)kc * B + mt * 64 + w * 16) * 48;
    #pragma unroll
    for (int rg = 0; rg < 4; ++rg) {
        int r = k8 * 4 + rg;
        pb[r * 48 +      r15] = a0[rg];
        pb[r * 48 + 16 + r15] = a1[rg];
        pb[r * 48 + 32 + r15] = a2[rg];
    }
}

// ---------------------------------------------------------------------------
// Reduce partials (coalesced float4, 192 parallel lanes) + bias + softmax.
// ---------------------------------------------------------------------------
__global__ __launch_bounds__(256) void k_soft(
    const float* __restrict__ part, const float* __restrict__ outb,
    float* __restrict__ out, int B)
{
    const int b = blockIdx.x, tid = threadIdx.x;
    __shared__ f32x4 red[16][12];
    __shared__ float vals[48];
    if (tid < 192) {
        int j = tid / 12, g = tid - j * 12;
        f32x4 s = {0.f, 0.f, 0.f, 0.f};
        for (int kc = j; kc < KSPLIT; kc += 16)
            s += *(const f32x4*)(part + ((size_t)kc * B + b) * 48 + g * 4);
        red[j][g] = s;
    }
    __syncthreads();
    if (tid < 12) {
        f32x4 s = red[0][tid];
        #pragma unroll
        for (int j = 1; j < 16; ++j) s += red[j][tid];
        #pragma unroll
        for (int e = 0; e < 4; ++e) {
            int o = tid * 4 + e;
            vals[o] = s[e] + ((o < 40) ? outb[o] : 0.f);
        }
    }
    __syncthreads();
    if (tid < 4) {
        float mx = -1e30f;
        #pragma unroll
        for (int j = 0; j < 10; ++j) mx = fmaxf(mx, vals[tid * 10 + j]);
        float e[10], s = 0.f;
        #pragma unroll
        for (int j = 0; j < 10; ++j) { e[j] = fexp2(LOG2E * (vals[tid * 10 + j] - mx)); s += e[j]; }
        float inv = frcp(s);
        #pragma unroll
        for (int j = 0; j < 10; ++j) out[b * 40 + tid * 10 + j] = e[j] * inv;
    }
}

// ---------------------------------------------------------------------------
extern "C" void kernel_launch(void* const* d_in, const int* in_sizes, int n_in,
                              void* d_out, int out_size, void* d_ws, size_t ws_size,
                              hipStream_t stream)
{
    const float* x     = (const float*)d_in[0];
    const float* encW  = (const float*)d_in[1];
    const float* eb_ih = (const float*)d_in[2];
    const float* eb_hh = (const float*)d_in[3];
    const float* decW  = (const float*)d_in[4];
    const float* db_ih = (const float*)d_in[5];
    const float* db_hh = (const float*)d_in[6];
    const float* outW  = (const float*)d_in[7];
    const float* outb  = (const float*)d_in[8];
    float* out = (float*)d_out;

    const int B = in_sizes[0] / (3 * 60 * TT);

    char* ws = (char*)d_ws;
    short* woutB = (short*)ws;                       // 48*21600*2 = 2,073,600 B
    short* wencP = (short*)(ws + 2073600);           // 288*192*2  =   110,592 B
    short* wdecP = (short*)(ws + 2184192);           // 288*96*2   =    55,296 B
    short* h2    = (short*)(ws + 2239488);           // B*21600*2  = B*43,200 B
    float* part  = (float*)(ws + 2239488 + (size_t)B * 43200);  // 45*B*48*4 B

    k_prep<<<dim3(831), dim3(256), 0, stream>>>(outW, encW, decW, woutB, wencP, wdecP);
    k_ed<<<dim3(B * 4), dim3(384), 0, stream>>>(x, wencP, wdecP, eb_ih, eb_hh,
                                                db_ih, db_hh, h2);
    k_out<<<dim3(KSPLIT * (B >> 6)), dim3(256), 0, stream>>>(h2, woutB, part, B);
    k_soft<<<dim3(B), dim3(256), 0, stream>>>(part, outb, out, B);
}